// Round 2
// baseline (235.601 us; speedup 1.0000x reference)
//
#include <hip/hip_runtime.h>
#include <math.h>

#define TOPK 13
#define PI_F 3.14159265358979323846f
#define CAP 128   // per-row positive-candidate buffer; exact fallback on overflow

typedef unsigned int u32;
typedef unsigned long long u64;

// monotone float -> uint mapping matching XLA total order
__device__ __forceinline__ u32 ford(float f) {
    u32 u = __float_as_uint(f);
    return (u & 0x80000000u) ? ~u : (u | 0x80000000u);
}
__device__ __forceinline__ float funord(u32 o) {
    u32 u = (o & 0x80000000u) ? (o & 0x7FFFFFFFu) : ~o;
    return __uint_as_float(u);
}

__device__ __forceinline__ float iou_fn(float4 g, float4 p) {
    float ltx = fmaxf(g.x, p.x), lty = fmaxf(g.y, p.y);
    float rbx = fminf(g.z, p.z), rby = fminf(g.w, p.w);
    float inter = fmaxf(rbx - ltx, 0.0f) * fmaxf(rby - lty, 0.0f);
    float a1 = fmaxf(g.z - g.x, 0.0f) * fmaxf(g.w - g.y, 0.0f);
    float a2 = fmaxf(p.z - p.x, 0.0f) * fmaxf(p.w - p.y, 0.0f);
    return inter / (((a1 + a2) - inter) + 1e-9f);
}

struct RowParams { float av, bar, offc, mx, mn; };

__device__ __forceinline__ RowParams row_params(float4 g) {
    float w = g.z - g.x, h = g.w - g.y;
    float ar = w / (h + 1e-5f);
    float ia = 1.0f / ar;
    RowParams rp;
    rp.av = ia / (2.0f - ia);
    rp.bar = 2.0f / ar;
    rp.offc = PI_F * (1.0f - 2.0f / (2.0f * ar));
    rp.mx = 0.5f + 0.5f * cosf(rp.offc);
    rp.mn = 0.5f + 0.5f * cosf(rp.bar * 90.0f / 180.0f * PI_F + rp.offc);
    return rp;
}

__device__ __forceinline__ float ang_measure(const RowParams& rp, float theta) {
    float cfv = 0.5f + 0.5f * cosf(rp.bar * theta / 180.0f * PI_F + rp.offc);
    float r = (cfv - rp.mn) / (rp.mx - rp.mn) * (1.0f - rp.av) + rp.av;
    return isnan(r) ? 0.0f : r;
}

// align in exact reference op order: (s**1 * iou**5) * ang**3, left-assoc
__device__ __forceinline__ float align_fn(float s, float iou, float r) {
    float iou2 = iou * iou;
    float iou5 = (iou2 * iou2) * iou;
    float r3 = (r * r) * r;
    return (s * iou5) * r3;
}

__device__ __forceinline__ void insert13(u64* arr, u64 key) {
    if (key > arr[TOPK - 1]) {
#pragma unroll
        for (int jj = 0; jj < TOPK; jj++) {
            u64 hi = arr[jj] > key ? arr[jj] : key;
            u64 lo = arr[jj] > key ? key : arr[jj];
            arr[jj] = hi;
            key = lo;
        }
    }
}

__global__ void k0_init(int* cnt, int* assign1, u32* pam, u32* pov, int* rowcnt,
                        int BA, int BN) {
    int t = blockIdx.x * blockDim.x + threadIdx.x;
    if (t < BA) { cnt[t] = 0; assign1[t] = -1; }
    if (t < BN) { pam[t] = 0x80000000u; pov[t] = 0x80000000u; rowcnt[t] = 0; } // ord(+0.0f)
}

// ---------------------------------------------------------------------------
// k1a: anchor-major pair scan. One thread per (batch, anchor). GT rows + their
// trig-derived params staged in LDS once per block; inner loop over n rows has
// ZERO global traffic on the common path. Emits positive candidates (v > 0)
// into per-row buffers. Zero-candidate (+0) semantics handled exactly in k1b.
// ---------------------------------------------------------------------------
__global__ __launch_bounds__(256)
void k1a_pairs(const float* __restrict__ scores, const float* __restrict__ pbox,
               const float* __restrict__ pang, const float* __restrict__ anc,
               const int* __restrict__ glab, const float* __restrict__ gbox,
               const float* __restrict__ gang, const float* __restrict__ mgt,
               int* __restrict__ rowcnt, u64* __restrict__ rowbuf,
               int bs, int A, int n, int C) {
    extern __shared__ float4 rowdat[];  // n * 3 float4: [g][av,bar,offc,ga][mx,mn,lab,active]
    int b = blockIdx.x % bs;            // batches spread across XCDs
    int chunk = blockIdx.x / bs;
    int tid = threadIdx.x;

    for (int i = tid; i < n; i += 256) {
        int bi = b * n + i;
        float4 g = ((const float4*)gbox)[bi];
        RowParams rp = row_params(g);   // bit-identical to k1b/k2's recompute
        float4 r1 = make_float4(rp.av, rp.bar, rp.offc, gang[bi]);
        float4 r2 = make_float4(rp.mx, rp.mn, __int_as_float(glab[bi]), mgt[bi]);
        rowdat[i * 3 + 0] = g;
        rowdat[i * 3 + 1] = r1;
        rowdat[i * 3 + 2] = r2;
    }
    __syncthreads();

    int a = chunk * 256 + tid;
    if (a >= A) return;

    float2 apt = ((const float2*)anc)[a];
    float4 p = ((const float4*)pbox)[(size_t)b * A + a];
    float pav = pang[(size_t)b * A + a];
    const float* sc = scores + ((size_t)b * A + a) * C;
    u32 akey = 0xFFFFFFFFu - (u32)a;

    for (int i = 0; i < n; i++) {
        float4 r2 = rowdat[i * 3 + 2];
        if (!(r2.w > 0.0f)) continue;   // masked gt row (uniform branch)
        float4 g = rowdat[i * 3 + 0];
        float mnv = fminf(fminf(apt.x - g.x, apt.y - g.y), fminf(g.z - apt.x, g.w - apt.y));
        float iou = iou_fn(g, p);       // straight-line: registers only
        if (mnv > 1e-9f && iou > 0.0f) {            // wave-any ~2.5% of rows
            float4 r1 = rowdat[i * 3 + 1];
            RowParams rp; rp.av = r1.x; rp.bar = r1.y; rp.offc = r1.z;
            rp.mx = r2.x; rp.mn = r2.y;
            float th = fabsf(r1.w - pav);
            float r = ang_measure(rp, th);
            if (r > 0.0f) {
                float s = sc[__float_as_int(r2.z)];  // scattered, rare
                float v = align_fn(s, iou, r);
                if (v > 0.0f) {
                    int bi = b * n + i;
                    int pos = atomicAdd(&rowcnt[bi], 1);
                    if (pos < CAP)
                        rowbuf[(size_t)bi * CAP + pos] = ((u64)ford(v) << 32) | (u64)akey;
                }
            }
        }
    }
}

// ---------------------------------------------------------------------------
// k1b: one wave per gt row. (1) Exact zero-candidate scan: walk anchors from
// index 0 in 64-chunks with the full classification (sign(+0) needs r) until
// the 13 lowest-index +0 anchors are found — typically one chunk. (2) Merge
// {buffer positives (or exact full rescan on overflow)} ∪ {13 lowest zeros}
// via 13 wave-max rounds; fire cnt/assign1 atomics with inside-gt recheck.
// ---------------------------------------------------------------------------
__global__ __launch_bounds__(64)
void k1b_select(const float* __restrict__ scores, const float* __restrict__ pbox,
                const float* __restrict__ pang, const float* __restrict__ anc,
                const int* __restrict__ glab, const float* __restrict__ gbox,
                const float* __restrict__ gang, const float* __restrict__ mgt,
                const int* __restrict__ rowcnt, const u64* __restrict__ rowbuf,
                int* __restrict__ cnt, int* __restrict__ assign1,
                int bs, int A, int n, int C) {
    int bi = blockIdx.x;
    int b = bi / n, i = bi - b * n;
    if (!(mgt[bi] > 0.0f)) return;      // masked row contributes nothing
    int lane = threadIdx.x;

    float4 g = ((const float4*)gbox)[bi];
    RowParams rp = row_params(g);
    float ga = gang[bi];
    int lab = glab[bi];
    const float4* pb = (const float4*)pbox + (size_t)b * A;
    const float* pa = pang + (size_t)b * A;
    const float2* ac = (const float2*)anc;
    const float* sc = scores + (size_t)b * A * C + lab;

    // ---- (1) 13 lowest-index +0 anchors, exact r0 classification ----
    __shared__ u64 zlist[16];
    int found = 0;
    for (int base = 0; base < A && found < 13; base += 64) {
        int a = base + lane;
        bool zc = false;
        if (a < A) {
            float2 apt = ac[a];
            float mnv = fminf(fminf(apt.x - g.x, apt.y - g.y), fminf(g.z - apt.x, g.w - apt.y));
            float4 p = pb[a];
            float iou = iou_fn(g, p);
            float th = fabsf(ga - pa[a]);
            float r = ang_measure(rp, th);
            bool na = (mnv > 1e-9f) && (iou > 0.0f);
            if (na && r > 0.0f) {
                float s = sc[(size_t)a * C];
                float v = align_fn(s, iou, r);
                zc = !(v > 0.0f);        // v == +0 exactly (s==0 / underflow)
            } else {
                zc = (r >= 0.0f);        // v == sign(r)*0; only +0 selectable
            }
        }
        u64 bal = __ballot(zc);
        int below = (int)__popcll(bal & ((1ull << lane) - 1ull));
        int idx = found + below;
        if (zc && idx < 13)
            zlist[idx] = (0x80000000ull << 32) | (u64)(0xFFFFFFFFu - (u32)a);
        found += (int)__popcll(bal);
    }
    __syncthreads();
    if (found > 13) found = 13;

    // ---- (2) gather positives ----
    u64 arr[TOPK];
#pragma unroll
    for (int jj = 0; jj < TOPK; jj++) arr[jj] = 0ull;
    int pc = rowcnt[bi];
    if (pc <= CAP) {
        const u64* buf = rowbuf + (size_t)bi * CAP;
        u64 ka = (lane < pc) ? buf[lane] : 0ull;
        u64 kb = (lane + 64 < pc) ? buf[lane + 64] : 0ull;
        arr[0] = ka > kb ? ka : kb;
        arr[1] = ka > kb ? kb : ka;
    } else {
        // overflow fallback: exact full-row rescan for positives
        for (int a = lane; a < A; a += 64) {
            float2 apt = ac[a];
            float mnv = fminf(fminf(apt.x - g.x, apt.y - g.y), fminf(g.z - apt.x, g.w - apt.y));
            if (!(mnv > 1e-9f)) continue;
            float4 p = pb[a];
            float iou = iou_fn(g, p);
            if (!(iou > 0.0f)) continue;
            float th = fabsf(ga - pa[a]);
            float r = ang_measure(rp, th);
            if (!(r > 0.0f)) continue;
            float s = sc[(size_t)a * C];
            float v = align_fn(s, iou, r);
            if (!(v > 0.0f)) continue;
            insert13(arr, ((u64)ford(v) << 32) | (u64)(0xFFFFFFFFu - (u32)a));
        }
    }

    // ---- (3) 13 wave-max rounds over positives ∪ zeros; atomics ----
    u64 kz = (lane < found) ? zlist[lane] : 0ull;
    for (int round = 0; round < TOPK; round++) {
        u64 m = arr[0] > kz ? arr[0] : kz;
#pragma unroll
        for (int st = 32; st > 0; st >>= 1) {
            u64 o = __shfl_xor(m, st, 64);
            if (o > m) m = o;
        }
        if (m == 0ull) break;           // uniform
        bool own = false;
        if (arr[0] == m) {              // keys unique -> exactly one owner lane
#pragma unroll
            for (int jj = 0; jj < TOPK - 1; jj++) arr[jj] = arr[jj + 1];
            arr[TOPK - 1] = 0ull;
            own = true;
        } else if (kz == m) {
            kz = 0ull;
            own = true;
        }
        if (own) {
            int a = (int)(0xFFFFFFFFu - (u32)(m & 0xFFFFFFFFull));
            float2 apt = ac[a];
            float mnv = fminf(fminf(apt.x - g.x, apt.y - g.y),
                              fminf(g.z - apt.x, g.w - apt.y));
            if (mnv > 1e-9f) {          // mask_pos = mask_topk * in_gts * mask_gt
                atomicAdd(&cnt[(size_t)b * A + a], 1);
                atomicMax(&assign1[(size_t)b * A + a], i);
            }
        }
    }
}

__global__ __launch_bounds__(256)
void k2_resolve(const float* __restrict__ scores, const float* __restrict__ pbox,
                const float* __restrict__ pang, const int* __restrict__ glab,
                const float* __restrict__ gbox, const float* __restrict__ gang,
                const int* __restrict__ cnt, const int* __restrict__ assign1,
                int* __restrict__ assign, float* __restrict__ alignv,
                u32* __restrict__ pam, u32* __restrict__ pov,
                int bs, int A, int n, int C) {
    int t = blockIdx.x * blockDim.x + threadIdx.x;
    if (t >= bs * A) return;
    int b = t / A;
    int c = cnt[t];
    int asg = -1;
    float alv = 0.0f;
    if (c > 0) {
        float4 p = ((const float4*)pbox)[t];
        if (c == 1) {
            asg = assign1[t];
        } else {
            // reference: overlaps.argmax(1) over ALL gt rows, first-max tie-break
            float best = -1.0f;
            asg = 0;
            for (int i = 0; i < n; i++) {
                float4 gi = ((const float4*)gbox)[b * n + i];
                float io = iou_fn(gi, p);
                if (io > best) { best = io; asg = i; }
            }
        }
        float4 g = ((const float4*)gbox)[b * n + asg];
        RowParams rp = row_params(g);
        float iou = iou_fn(g, p);
        float th = fabsf(gang[b * n + asg] - pang[t]);
        float r = ang_measure(rp, th);
        float s = scores[(size_t)t * C + glab[b * n + asg]];
        alv = align_fn(s, iou, r);
        atomicMax(&pam[b * n + asg], ford(alv));
        atomicMax(&pov[b * n + asg], ford(iou));
    }
    assign[t] = asg;
    alignv[t] = alv;
}

__global__ __launch_bounds__(256)
void k3_out(const int* __restrict__ glab, const float* __restrict__ gbox,
            const float* __restrict__ gang, const int* __restrict__ assign,
            const float* __restrict__ alignv, const u32* __restrict__ pam,
            const u32* __restrict__ pov, float* __restrict__ out,
            int bs, int A, int n, int C) {
    __shared__ float s_nv[256];
    __shared__ int s_lf[256];
    int tid = threadIdx.x;
    int base = blockIdx.x * 256;
    int t = base + tid;
    int BA = bs * A;

    if (t < BA) {
        int b = t / A;
        int asg = assign[t];
        bool fg = asg >= 0;
        int tgt = fg ? asg : 0;  // argmax of all-zero column -> row 0
        int lb = glab[b * n + tgt];
        if (lb < 0) lb = 0;

        float* o_tlab = out;
        float* o_tbb = out + BA;
        float* o_tang = out + (size_t)BA * 5;
        float* o_fg = out + (size_t)BA * 6 + (size_t)BA * C;

        o_tlab[t] = (float)lb;
        ((float4*)o_tbb)[t] = ((const float4*)gbox)[b * n + tgt];
        o_tang[t] = gang[b * n + tgt];
        o_fg[t] = fg ? 1.0f : 0.0f;

        float nv = 0.0f;
        if (fg) {
            float pamv = funord(pam[b * n + asg]);
            float povv = funord(pov[b * n + asg]);
            float vv = (alignv[t] * povv) / (pamv + 1e-9f);
            nv = fmaxf(vv, 0.0f);  // 59 other rows contribute exactly 0 to the max
        }
        s_nv[tid] = nv;
        s_lf[tid] = fg ? lb : -1;
    } else {
        s_nv[tid] = 0.0f;
        s_lf[tid] = -1;
    }
    __syncthreads();

    // ts: coalesced float4 writes, (anchor, class-quad) with quad fastest
    int Q = C / 4;  // 20
    int nA = min(256, BA - base);
    if (nA <= 0) return;
    int total = nA * Q;
    float4* o_ts = (float4*)(out + (size_t)BA * 6) + (size_t)base * Q;
    for (int idx = tid; idx < total; idx += 256) {
        int tl = idx / Q;
        int q = idx - tl * Q;
        float nv = s_nv[tl];
        int lf = s_lf[tl];
        int cb = q * 4;
        float4 o;
        o.x = (lf == cb) ? nv : 0.0f;
        o.y = (lf == cb + 1) ? nv : 0.0f;
        o.z = (lf == cb + 2) ? nv : 0.0f;
        o.w = (lf == cb + 3) ? nv : 0.0f;
        o_ts[idx] = o;
    }
}

extern "C" void kernel_launch(void* const* d_in, const int* in_sizes, int n_in,
                              void* d_out, int out_size, void* d_ws, size_t ws_size,
                              hipStream_t stream) {
    const float* scores = (const float*)d_in[0];
    const float* pbox = (const float*)d_in[1];
    const float* pang = (const float*)d_in[2];
    const float* anc = (const float*)d_in[3];
    const int* glab = (const int*)d_in[4];
    const float* gbox = (const float*)d_in[5];
    const float* gang = (const float*)d_in[6];
    const float* mgt = (const float*)d_in[7];

    const int C = 80;
    int A = in_sizes[3] / 2;
    int bs = in_sizes[0] / (A * C);
    int n = in_sizes[4] / bs;
    int BA = bs * A;
    int BN = bs * n;

    char* ws = (char*)d_ws;
    u64* rowbuf = (u64*)ws;     ws += sizeof(u64) * (size_t)BN * CAP;  // 8B-aligned first
    int* cnt = (int*)ws;        ws += sizeof(int) * (size_t)BA;
    int* assign1 = (int*)ws;    ws += sizeof(int) * (size_t)BA;
    int* assign = (int*)ws;     ws += sizeof(int) * (size_t)BA;
    float* alignv = (float*)ws; ws += sizeof(float) * (size_t)BA;
    u32* pam = (u32*)ws;        ws += sizeof(u32) * (size_t)BN;
    u32* pov = (u32*)ws;        ws += sizeof(u32) * (size_t)BN;
    int* rowcnt = (int*)ws;     ws += sizeof(int) * (size_t)BN;

    int nCh = (A + 255) / 256;
    size_t ldsz = (size_t)n * 3 * sizeof(float4);

    k0_init<<<(BA + 255) / 256, 256, 0, stream>>>(cnt, assign1, pam, pov, rowcnt, BA, BN);
    k1a_pairs<<<bs * nCh, 256, ldsz, stream>>>(scores, pbox, pang, anc, glab, gbox, gang,
                                               mgt, rowcnt, rowbuf, bs, A, n, C);
    k1b_select<<<BN, 64, 0, stream>>>(scores, pbox, pang, anc, glab, gbox, gang, mgt,
                                      rowcnt, rowbuf, cnt, assign1, bs, A, n, C);
    k2_resolve<<<(BA + 255) / 256, 256, 0, stream>>>(scores, pbox, pang, glab, gbox, gang,
                                                     cnt, assign1, assign, alignv, pam, pov,
                                                     bs, A, n, C);
    k3_out<<<(BA + 255) / 256, 256, 0, stream>>>(glab, gbox, gang, assign, alignv, pam, pov,
                                                 (float*)d_out, bs, A, n, C);
}

// Round 3
// 170.038 us; speedup vs baseline: 1.3856x; 1.3856x over previous
//
#include <hip/hip_runtime.h>
#include <math.h>

#define TOPK 13
#define PI_F 3.14159265358979323846f
#define K1_THREADS 256
#define K1_WAVES (K1_THREADS / 64)

typedef unsigned int u32;
typedef unsigned long long u64;

// monotone float -> uint mapping matching XLA total order
__device__ __forceinline__ u32 ford(float f) {
    u32 u = __float_as_uint(f);
    return (u & 0x80000000u) ? ~u : (u | 0x80000000u);
}
__device__ __forceinline__ float funord(u32 o) {
    u32 u = (o & 0x80000000u) ? (o & 0x7FFFFFFFu) : ~o;
    return __uint_as_float(u);
}

__device__ __forceinline__ float iou_fn(float4 g, float4 p) {
    float ltx = fmaxf(g.x, p.x), lty = fmaxf(g.y, p.y);
    float rbx = fminf(g.z, p.z), rby = fminf(g.w, p.w);
    float inter = fmaxf(rbx - ltx, 0.0f) * fmaxf(rby - lty, 0.0f);
    float a1 = fmaxf(g.z - g.x, 0.0f) * fmaxf(g.w - g.y, 0.0f);
    float a2 = fmaxf(p.z - p.x, 0.0f) * fmaxf(p.w - p.y, 0.0f);
    return inter / (((a1 + a2) - inter) + 1e-9f);
}

struct RowParams { float av, bar, offc, mx, mn; };

__device__ __forceinline__ RowParams row_params(float4 g) {
    float w = g.z - g.x, h = g.w - g.y;
    float ar = w / (h + 1e-5f);
    float ia = 1.0f / ar;
    RowParams rp;
    rp.av = ia / (2.0f - ia);
    rp.bar = 2.0f / ar;
    rp.offc = PI_F * (1.0f - 2.0f / (2.0f * ar));
    rp.mx = 0.5f + 0.5f * cosf(rp.offc);
    rp.mn = 0.5f + 0.5f * cosf(rp.bar * 90.0f / 180.0f * PI_F + rp.offc);
    return rp;
}

__device__ __forceinline__ float ang_measure(const RowParams& rp, float theta) {
    float cfv = 0.5f + 0.5f * cosf(rp.bar * theta / 180.0f * PI_F + rp.offc);
    float r = (cfv - rp.mn) / (rp.mx - rp.mn) * (1.0f - rp.av) + rp.av;
    return isnan(r) ? 0.0f : r;
}

// align in exact reference op order: (s**1 * iou**5) * ang**3, left-assoc
__device__ __forceinline__ float align_fn(float s, float iou, float r) {
    float iou2 = iou * iou;
    float iou5 = (iou2 * iou2) * iou;
    float r3 = (r * r) * r;
    return (s * iou5) * r3;
}

__global__ void k0_init(int* cnt, int* assign1, u32* pam, u32* pov, int BA, int BN) {
    int t = blockIdx.x * blockDim.x + threadIdx.x;
    if (t < BA) { cnt[t] = 0; assign1[t] = -1; }
    if (t < BN) { pam[t] = 0x80000000u; pov[t] = 0x80000000u; } // ord(+0.0f)
}

// ---------------------------------------------------------------------------
// k1: one block per (batch, gt-row). Loads are straight-line & unconditional
// (so the compiler pipelines them across iterations — round-1 lesson); only
// the transcendental path + scattered score load are conditional (round-0
// lesson: unconditional cosf dominated VALU). Epilogue: per-wave top-13 with
// zero barriers, then wave 0 merges 4 sorted lists (one __syncthreads total).
// ---------------------------------------------------------------------------
__global__ __launch_bounds__(K1_THREADS)
void k1_topk(const float* __restrict__ scores, const float* __restrict__ pbox,
             const float* __restrict__ pang, const float* __restrict__ anc,
             const int* __restrict__ glab, const float* __restrict__ gbox,
             const float* __restrict__ gang, const float* __restrict__ mgt,
             int* __restrict__ cnt, int* __restrict__ assign1,
             int bs, int A, int n, int C) {
    int j = blockIdx.x;
    // XCD clustering: blocks of the same batch land on the same XCD (j % 8 == b % 8)
    int b = j % bs;
    int i = j / bs;
    int bi = b * n + i;
    int tid = threadIdx.x;

    float mg = mgt[bi];
    if (!(mg > 0.0f)) return;   // masked row: reference wipes it (cnt>1 at idx0 / mask mult)

    float4 g = ((const float4*)gbox)[bi];
    int lab = glab[bi];
    float ga = gang[bi];
    RowParams rp = row_params(g);

    const float4* pb = ((const float4*)pbox) + (size_t)b * A;
    const float* pa = pang + (size_t)b * A;
    const float2* ac = (const float2*)anc;
    const float* sc = scores + (size_t)b * A * C + lab;

    u64 arr[TOPK];
#pragma unroll
    for (int jj = 0; jj < TOPK; jj++) arr[jj] = 0ull;
    u64 zkey = 0ull;  // thread's lowest-index exact-+0 candidate

    // Exactness of the conditional-r path (reference v = align*in_gts,
    // align = (s*iou^5)*r^3, s>=0, iou>=0, r finite after NaN-replace):
    //  - !inGt or iou==0  -> v = +/-0 with sign(r); selectable only if +0.
    //  - inGt && iou>0    -> r>0: v = align (insert if >0, else +0 cand);
    //                       r==0: +0 cand; r<0: v<0 never selectable.
    //  sign(r) is only consumed while zkey is unset, so r (the cosf) can be
    //  skipped once this thread holds its lowest-index zero candidate.
    for (int a = tid; a < A; a += K1_THREADS) {
        // ALL global loads unconditional & induction-addressed: pipelineable.
        float4 p = pb[a];
        float pav = pa[a];
        float2 apt = ac[a];
        float iou = iou_fn(g, p);
        float mnv = fminf(fminf(apt.x - g.x, apt.y - g.y), fminf(g.z - apt.x, g.w - apt.y));
        bool needAlign = (mnv > 1e-9f) && (iou > 0.0f);
        if (needAlign || zkey == 0ull) {
            float th = fabsf(ga - pav);
            float r = ang_measure(rp, th);
            bool zeroCand;
            if (needAlign && r > 0.0f) {
                float s = sc[(size_t)a * C];   // scattered load, rare path only
                float v = align_fn(s, iou, r);
                if (v > 0.0f) {
                    zeroCand = false;
                    u64 key = ((u64)ford(v) << 32) | (u64)(0xFFFFFFFFu - (u32)a);
                    if (key > arr[TOPK - 1]) {
#pragma unroll
                        for (int jj = 0; jj < TOPK; jj++) {
                            u64 hi = arr[jj] > key ? arr[jj] : key;
                            u64 lo = arr[jj] > key ? key : arr[jj];
                            arr[jj] = hi;
                            key = lo;
                        }
                    }
                } else {
                    zeroCand = true;  // s==0 or iou^5 underflow -> v == +0 exactly
                }
            } else {
                zeroCand = (r >= 0.0f);  // v == sign(r)*0; only +0 is selectable
            }
            if (zeroCand && zkey == 0ull) {
                zkey = (0x80000000ull << 32) | (u64)(0xFFFFFFFFu - (u32)a);
            }
        }
    }
    // merge the single zero candidate (sufficient per thread: the 13
    // lowest-index zero candidates land on distinct threads at stride 256)
    if (zkey > arr[TOPK - 1]) {
        u64 key = zkey;
#pragma unroll
        for (int jj = 0; jj < TOPK; jj++) {
            u64 hi = arr[jj] > key ? arr[jj] : key;
            u64 lo = arr[jj] > key ? key : arr[jj];
            arr[jj] = hi;
            key = lo;
        }
    }

    // Phase 1: per-wave top-13 (no barriers; keys unique, 0 = empty).
    __shared__ u64 wtop[K1_WAVES * TOPK];
    int lane = tid & 63, wv = tid >> 6;
    for (int round = 0; round < TOPK; round++) {
        u64 m = arr[0];
#pragma unroll
        for (int st = 32; st > 0; st >>= 1) {
            u64 o = __shfl_xor(m, st, 64);
            if (o > m) m = o;
        }
        if (lane == 0) wtop[wv * TOPK + round] = m;
        if (arr[0] == m && m != 0ull) {  // unique winner pops its head
#pragma unroll
            for (int jj = 0; jj < TOPK - 1; jj++) arr[jj] = arr[jj + 1];
            arr[TOPK - 1] = 0ull;
        }
    }
    __syncthreads();

    // Phase 2: wave 0 merges the 4 sorted 13-lists (52 keys, one per lane)
    // and fires the atomics for the block top-13.
    if (wv == 0) {
        const int NK = K1_WAVES * TOPK;  // 52
        u64 ka = (lane < NK) ? wtop[lane] : 0ull;
        for (int round = 0; round < TOPK; round++) {
            u64 m = ka;
#pragma unroll
            for (int st = 32; st > 0; st >>= 1) {
                u64 o = __shfl_xor(m, st, 64);
                if (o > m) m = o;
            }
            if (m == 0ull) break;        // uniform across wave 0 -> safe
            if (ka == m) {               // unique owner lane processes the winner
                ka = 0ull;
                int a = (int)(0xFFFFFFFFu - (u32)(m & 0xFFFFFFFFull));
                float2 apt = ac[a];
                float mnv = fminf(fminf(apt.x - g.x, apt.y - g.y),
                                  fminf(g.z - apt.x, g.w - apt.y));
                if (mnv > 1e-9f) {  // mask_pos = mask_topk * in_gts * mask_gt
                    atomicAdd(&cnt[(size_t)b * A + a], 1);
                    atomicMax(&assign1[(size_t)b * A + a], i);
                }
            }
        }
    }
}

__global__ __launch_bounds__(256)
void k2_resolve(const float* __restrict__ scores, const float* __restrict__ pbox,
                const float* __restrict__ pang, const int* __restrict__ glab,
                const float* __restrict__ gbox, const float* __restrict__ gang,
                const int* __restrict__ cnt, const int* __restrict__ assign1,
                int* __restrict__ assign, float* __restrict__ alignv,
                u32* __restrict__ pam, u32* __restrict__ pov,
                int bs, int A, int n, int C) {
    int t = blockIdx.x * blockDim.x + threadIdx.x;
    if (t >= bs * A) return;
    int b = t / A;
    int c = cnt[t];
    int asg = -1;
    float alv = 0.0f;
    if (c > 0) {
        float4 p = ((const float4*)pbox)[t];
        if (c == 1) {
            asg = assign1[t];
        } else {
            // reference: overlaps.argmax(1) over ALL gt rows, first-max tie-break
            float best = -1.0f;
            asg = 0;
            for (int i = 0; i < n; i++) {
                float4 gi = ((const float4*)gbox)[b * n + i];
                float io = iou_fn(gi, p);
                if (io > best) { best = io; asg = i; }
            }
        }
        float4 g = ((const float4*)gbox)[b * n + asg];
        RowParams rp = row_params(g);
        float iou = iou_fn(g, p);
        float th = fabsf(gang[b * n + asg] - pang[t]);
        float r = ang_measure(rp, th);
        float s = scores[(size_t)t * C + glab[b * n + asg]];
        alv = align_fn(s, iou, r);
        atomicMax(&pam[b * n + asg], ford(alv));
        atomicMax(&pov[b * n + asg], ford(iou));
    }
    assign[t] = asg;
    alignv[t] = alv;
}

__global__ __launch_bounds__(256)
void k3_out(const int* __restrict__ glab, const float* __restrict__ gbox,
            const float* __restrict__ gang, const int* __restrict__ assign,
            const float* __restrict__ alignv, const u32* __restrict__ pam,
            const u32* __restrict__ pov, float* __restrict__ out,
            int bs, int A, int n, int C) {
    __shared__ float s_nv[256];
    __shared__ int s_lf[256];
    int tid = threadIdx.x;
    int base = blockIdx.x * 256;
    int t = base + tid;
    int BA = bs * A;

    if (t < BA) {
        int b = t / A;
        int asg = assign[t];
        bool fg = asg >= 0;
        int tgt = fg ? asg : 0;  // argmax of all-zero column -> row 0
        int lb = glab[b * n + tgt];
        if (lb < 0) lb = 0;

        float* o_tlab = out;
        float* o_tbb = out + BA;
        float* o_tang = out + (size_t)BA * 5;
        float* o_fg = out + (size_t)BA * 6 + (size_t)BA * C;

        o_tlab[t] = (float)lb;
        ((float4*)o_tbb)[t] = ((const float4*)gbox)[b * n + tgt];
        o_tang[t] = gang[b * n + tgt];
        o_fg[t] = fg ? 1.0f : 0.0f;

        float nv = 0.0f;
        if (fg) {
            float pamv = funord(pam[b * n + asg]);
            float povv = funord(pov[b * n + asg]);
            float vv = (alignv[t] * povv) / (pamv + 1e-9f);
            nv = fmaxf(vv, 0.0f);  // 59 other rows contribute exactly 0 to the max
        }
        s_nv[tid] = nv;
        s_lf[tid] = fg ? lb : -1;
    } else {
        s_nv[tid] = 0.0f;
        s_lf[tid] = -1;
    }
    __syncthreads();

    // ts: coalesced float4 writes, (anchor, class-quad) with quad fastest
    int Q = C / 4;  // 20
    int nA = min(256, BA - base);
    if (nA <= 0) return;
    int total = nA * Q;
    float4* o_ts = (float4*)(out + (size_t)BA * 6) + (size_t)base * Q;
    for (int idx = tid; idx < total; idx += 256) {
        int tl = idx / Q;
        int q = idx - tl * Q;
        float nv = s_nv[tl];
        int lf = s_lf[tl];
        int cb = q * 4;
        float4 o;
        o.x = (lf == cb) ? nv : 0.0f;
        o.y = (lf == cb + 1) ? nv : 0.0f;
        o.z = (lf == cb + 2) ? nv : 0.0f;
        o.w = (lf == cb + 3) ? nv : 0.0f;
        o_ts[idx] = o;
    }
}

extern "C" void kernel_launch(void* const* d_in, const int* in_sizes, int n_in,
                              void* d_out, int out_size, void* d_ws, size_t ws_size,
                              hipStream_t stream) {
    const float* scores = (const float*)d_in[0];
    const float* pbox = (const float*)d_in[1];
    const float* pang = (const float*)d_in[2];
    const float* anc = (const float*)d_in[3];
    const int* glab = (const int*)d_in[4];
    const float* gbox = (const float*)d_in[5];
    const float* gang = (const float*)d_in[6];
    const float* mgt = (const float*)d_in[7];

    const int C = 80;
    int A = in_sizes[3] / 2;
    int bs = in_sizes[0] / (A * C);
    int n = in_sizes[4] / bs;
    int BA = bs * A;
    int BN = bs * n;

    char* ws = (char*)d_ws;
    int* cnt = (int*)ws;        ws += sizeof(int) * (size_t)BA;
    int* assign1 = (int*)ws;    ws += sizeof(int) * (size_t)BA;
    int* assign = (int*)ws;     ws += sizeof(int) * (size_t)BA;
    float* alignv = (float*)ws; ws += sizeof(float) * (size_t)BA;
    u32* pam = (u32*)ws;        ws += sizeof(u32) * (size_t)BN;
    u32* pov = (u32*)ws;        ws += sizeof(u32) * (size_t)BN;

    k0_init<<<(BA + 255) / 256, 256, 0, stream>>>(cnt, assign1, pam, pov, BA, BN);
    k1_topk<<<BN, K1_THREADS, 0, stream>>>(scores, pbox, pang, anc, glab, gbox, gang, mgt,
                                           cnt, assign1, bs, A, n, C);
    k2_resolve<<<(BA + 255) / 256, 256, 0, stream>>>(scores, pbox, pang, glab, gbox, gang,
                                                     cnt, assign1, assign, alignv, pam, pov,
                                                     bs, A, n, C);
    k3_out<<<(BA + 255) / 256, 256, 0, stream>>>(glab, gbox, gang, assign, alignv, pam, pov,
                                                 (float*)d_out, bs, A, n, C);
}